// Round 1
// 458.152 us; speedup vs baseline: 1.0130x; 1.0130x over previous
//
#include <hip/hip_runtime.h>

#define T_LEN   2000
#define K_FR    400
#define K_D     400
#define A_DIM   100
#define N_ROWS  (T_LEN * K_FR)     // 800000
#define RPB     64                 // rows per tile
#define TILE_F  (RPB * A_DIM)      // 6400 floats = 25.6 KB
#define NBATCH  (N_ROWS / RPB)     // 12500 (exact)
#define EPSF    1e-24f
#define MAIN_BLOCKS 1024

// ws layout:
//   [0,8)      double mmd_grad_acc
//   [8,408)    float  gtheta_acc[100]
//   [416,2016) float  c[400]

__global__ void mmdglm_setup(const float* __restrict__ phi_d,
                             const float* __restrict__ phi_fr,
                             float* __restrict__ c,
                             float* __restrict__ gth_acc,
                             double* __restrict__ mmdg_acc,
                             float* __restrict__ out)
{
    __shared__ float w1[8], w2[8], w3[8], w4[8];
    __shared__ float sums[4];
    const int tid = threadIdx.x;  // 512 threads
    const float vfr = (tid < K_FR) ? phi_fr[tid] : 0.f;
    const float vd  = (tid < K_D)  ? phi_d[tid]  : 0.f;
    float s1 = vfr, s2 = vfr * vfr, s3 = vd, s4 = vd * vd;
    #pragma unroll
    for (int off = 1; off < 64; off <<= 1) {
        s1 += __shfl_xor(s1, off);
        s2 += __shfl_xor(s2, off);
        s3 += __shfl_xor(s3, off);
        s4 += __shfl_xor(s4, off);
    }
    const int wave = tid >> 6, lane = tid & 63;
    if (lane == 0) { w1[wave] = s1; w2[wave] = s2; w3[wave] = s3; w4[wave] = s4; }
    __syncthreads();
    if (tid == 0) {
        float a = 0, b = 0, cc = 0, d = 0;
        for (int i = 0; i < 8; ++i) { a += w1[i]; b += w2[i]; cc += w3[i]; d += w4[i]; }
        sums[0] = a; sums[1] = b; sums[2] = cc; sums[3] = d;
    }
    __syncthreads();
    const float S_fr = sums[0], Q_fr = sums[1], S_d = sums[2], Q_d = sums[3];
    const float n_fr = (float)(K_FR * (K_FR - 1) / 2);
    const float n_d  = (float)(K_D * (K_D - 1) / 2);
    if (tid < K_FR) {
        const float p = phi_fr[tid];
        c[tid] = (S_fr * p - p * p) / n_fr
               - 2.0f * S_d * p / (float)(K_D * K_FR);
    }
    if (tid < A_DIM) gth_acc[tid] = 0.f;
    if (tid == 511) *mmdg_acc = 0.0;
    if (tid == 0) {
        const float mmd = (S_d * S_d - Q_d) / (2.0f * n_d)
                        + (S_fr * S_fr - Q_fr) / (2.0f * n_fr)
                        - 2.0f * S_d * S_fr / (float)(K_D * K_FR);
        out[101] = mmd;
    }
}

// Async global->LDS staging of one 64x100 tile (25 chunks of 64 lanes x 16B).
// LDS dest is wave-uniform base; HW scatters lane*16 (linear layout, matches tile).
__device__ __forceinline__ void stage_tile(const float* __restrict__ g0,
                                           float* l0, int wave, int lane)
{
    for (int c = wave; c < 25; c += 4) {
        const float* g = g0 + (c << 8) + (lane << 2);   // chunk c, lane's 16B
        float* l = l0 + (c << 8);                       // wave-uniform LDS base
        __builtin_amdgcn_global_load_lds(
            (const __attribute__((address_space(1))) void*)g,
            (__attribute__((address_space(3))) void*)l, 16, 0, 0);
    }
}

__global__ __launch_bounds__(256)
void mmdglm_main(const float* __restrict__ X,
                 const int*   __restrict__ mask,
                 const float* __restrict__ theta,
                 const float* __restrict__ tvec,
                 const float* __restrict__ c,
                 float*  __restrict__ gth_acc,
                 double* __restrict__ mmdg_acc)
{
    // double-buffered tile: 2 x 25.6 KB = 51.2 KB -> 3 blocks/CU
    __shared__ __align__(16) float buf[2][TILE_F];
    __shared__ float lred[4];
    const int tid  = threadIdx.x;
    const int wave = tid >> 6, lane = tid & 63;
    const int slot = tid >> 2;   // 0..63 : row within tile
    const int part = tid & 3;    // 0..3  : 25-element chunk of A

    float th[25];
    #pragma unroll
    for (int j = 0; j < 25; ++j) th[j] = theta[part * 25 + j];

    const float dt = tvec[1] - tvec[0];

    float acc[25];
    #pragma unroll
    for (int j = 0; j < 25; ++j) acc[j] = 0.f;
    float llacc = 0.f;

    // prologue: issue async loads for this block's first tile
    int t = blockIdx.x;
    stage_tile(X + (size_t)t * TILE_F, buf[0], wave, lane);
    int cur = 0;

    for (; t < NBATCH; t += gridDim.x) {
        // barrier: compiler drains vmcnt(0) here -> buf[cur] is complete,
        // and every wave is done reading buf[cur^1] from last iteration.
        __syncthreads();

        const int tn = t + (int)gridDim.x;
        if (tn < NBATCH)   // issue next tile's loads; they fly during compute
            stage_tile(X + (size_t)tn * TILE_F, buf[cur ^ 1], wave, lane);

        const int row = t * RPB + slot;
        const float* xp = buf[cur] + 25 * tid;   // slot*100 + part*25
        float x[25];
        float u = 0.f;
        #pragma unroll
        for (int j = 0; j < 25; ++j) { x[j] = xp[j]; u = fmaf(x[j], th[j], u); }
        u += __shfl_xor(u, 1);
        u += __shfl_xor(u, 2);   // all 4 quad lanes now hold full dot

        const float r  = __expf(u);
        const int   m  = mask[row];
        const float ck = c[row - (row / K_FR) * K_FR];
        float w, llt;
        if (m) {
            const float eneg = __expf(-dt * r);
            const float epos = __expf(dt * r);
            llt = __logf(1.0f - eneg + EPSF);
            w   = dt * r / (epos - 1.0f - EPSF);
        } else {
            llt = -dt * r;
            w   = -dt * r;
        }
        const float cw = ck * w;
        if (part == 0) llacc = fmaf(ck, llt, llacc);
        #pragma unroll
        for (int j = 0; j < 25; ++j) acc[j] = fmaf(cw, x[j], acc[j]);

        cur ^= 1;
    }
    __syncthreads();   // all compute done; safe to reuse buf[0] as scratch

    // ---- block reduce grad_theta: reuse buf[0] as red[256][25] ----
    float* red = &buf[0][0];
    #pragma unroll
    for (int j = 0; j < 25; ++j) red[tid * 25 + j] = acc[j];
    __syncthreads();
    if (tid < A_DIM) {
        const int p = tid / 25, j = tid - p * 25;   // a = p*25 + j
        float s = 0.f;
        for (int sl = 0; sl < RPB; ++sl)
            s += red[(sl * 4 + p) * 25 + j];
        atomicAdd(&gth_acc[tid], s);
    }

    // ---- block reduce mmd_grad partial ----
    float l = llacc;
    #pragma unroll
    for (int off = 1; off < 64; off <<= 1) l += __shfl_xor(l, off);
    if (lane == 0) lred[wave] = l;
    __syncthreads();
    if (tid == 0)
        atomicAdd(mmdg_acc, (double)(lred[0] + lred[1] + lred[2] + lred[3]));
}

__global__ void mmdglm_finalize(const double* __restrict__ mmdg_acc,
                                const float* __restrict__ gth_acc,
                                float* __restrict__ out)
{
    const int tid = threadIdx.x;
    if (tid == 0) out[0] = (float)(*mmdg_acc);
    if (tid >= 1 && tid <= 100) out[tid] = gth_acc[tid - 1];
}

extern "C" void kernel_launch(void* const* d_in, const int* in_sizes, int n_in,
                              void* d_out, int out_size, void* d_ws, size_t ws_size,
                              hipStream_t stream) {
    const float* t      = (const float*)d_in[0];
    const int*   mask   = (const int*)  d_in[1];
    const float* X      = (const float*)d_in[2];
    const float* theta  = (const float*)d_in[3];
    const float* phi_d  = (const float*)d_in[4];
    const float* phi_fr = (const float*)d_in[5];
    float* out = (float*)d_out;

    char* ws = (char*)d_ws;
    double* mmdg_acc = (double*)ws;
    float*  gth_acc  = (float*)(ws + 8);
    float*  c        = (float*)(ws + 416);

    mmdglm_setup<<<1, 512, 0, stream>>>(phi_d, phi_fr, c, gth_acc, mmdg_acc, out);
    mmdglm_main<<<MAIN_BLOCKS, 256, 0, stream>>>(X, mask, theta, t, c, gth_acc, mmdg_acc);
    mmdglm_finalize<<<1, 128, 0, stream>>>(mmdg_acc, gth_acc, out);
}

// Round 3
// 436.150 us; speedup vs baseline: 1.0641x; 1.0504x over previous
//
#include <hip/hip_runtime.h>

#define T_LEN   2000
#define K_FR    400
#define K_D     400
#define A_DIM   100
#define N_ROWS  (T_LEN * K_FR)     // 800000
#define RPB     64                 // rows per tile
#define TILE_F  (RPB * A_DIM)      // 6400 floats = 25.6 KB
#define NBATCH  (N_ROWS / RPB)     // 12500 (exact)
#define EPSF    1e-24f
#define GRID    768                // 3 blocks/CU * 256 CUs, all co-resident

// ws layout:
//   [0, 307200)        float ws_g[A_DIM][GRID]  per-block grad_theta partials
//   [307200, 310272)   float ws_ll[GRID]        per-block ll partials

// Async global->LDS staging of one 64x100 tile (25 chunks of 64 lanes x 16B).
// LDS dest is wave-uniform base; HW scatters lane*16 (linear layout, matches tile).
__device__ __forceinline__ void stage_tile(const float* __restrict__ g0,
                                           float* l0, int wave, int lane)
{
    for (int c = wave; c < 25; c += 4) {
        const float* g = g0 + (c << 8) + (lane << 2);   // chunk c, lane's 16B
        float* l = l0 + (c << 8);                       // wave-uniform LDS base
        __builtin_amdgcn_global_load_lds(
            (const __attribute__((address_space(1))) void*)g,
            (__attribute__((address_space(3))) void*)l, 16, 0, 0);
    }
}

__global__ __launch_bounds__(256, 3)   // force <=170 VGPR -> 3 blocks/CU with 51.2KB LDS
void mmdglm_main(const float* __restrict__ X,
                 const int*   __restrict__ mask,
                 const float* __restrict__ theta,
                 const float* __restrict__ tvec,
                 const float* __restrict__ phi_d,
                 const float* __restrict__ phi_fr,
                 float* __restrict__ ws_g,
                 float* __restrict__ ws_ll,
                 float* __restrict__ out)
{
    // double-buffered tile: 2 x 25.6 KB = 51.2 KB
    __shared__ __align__(16) float buf[2][TILE_F];
    __shared__ float psum[4][4];   // phi partial sums (never overwritten)
    __shared__ float lsum[4];      // ll block reduce
    const int tid  = threadIdx.x;
    const int wave = tid >> 6, lane = tid & 63;
    const int slot = tid >> 2;   // 0..63 : row within tile
    const int part = tid & 3;    // 0..3  : 25-element chunk of A
    const int bid  = blockIdx.x;

    // prologue: issue async loads for this block's first tile; they fly
    // while phase 0 (phi sums) computes.
    stage_tile(X + (size_t)bid * TILE_F, buf[0], wave, lane);

    // ---- phase 0: per-block (redundant) phi sums ----
    float s1 = 0.f, s2 = 0.f, s3 = 0.f, s4 = 0.f;
    for (int i = tid; i < K_FR; i += 256) { const float p = phi_fr[i]; s1 += p; s2 += p * p; }
    for (int i = tid; i < K_D;  i += 256) { const float p = phi_d[i];  s3 += p; s4 += p * p; }
    #pragma unroll
    for (int off = 1; off < 64; off <<= 1) {
        s1 += __shfl_xor(s1, off);
        s2 += __shfl_xor(s2, off);
        s3 += __shfl_xor(s3, off);
        s4 += __shfl_xor(s4, off);
    }
    if (lane == 0) { psum[0][wave] = s1; psum[1][wave] = s2; psum[2][wave] = s3; psum[3][wave] = s4; }
    __syncthreads();
    const float S_fr = psum[0][0] + psum[0][1] + psum[0][2] + psum[0][3];
    const float S_d  = psum[2][0] + psum[2][1] + psum[2][2] + psum[2][3];

    const float n_fr    = (float)(K_FR * (K_FR - 1) / 2);   // 79800
    const float inv_nfr = 1.0f / n_fr;
    const float C2      = S_d * (2.0f / (float)(K_D * K_FR));

    // mmd output: written once, here, so Q_* die before the hot loop
    if (bid == 0 && tid == 0) {
        const float Q_fr = psum[1][0] + psum[1][1] + psum[1][2] + psum[1][3];
        const float Q_d  = psum[3][0] + psum[3][1] + psum[3][2] + psum[3][3];
        const float n_d  = (float)(K_D * (K_D - 1) / 2);
        out[101] = (S_d * S_d - Q_d) / (2.0f * n_d)
                 + (S_fr * S_fr - Q_fr) / (2.0f * n_fr)
                 - 2.0f * S_d * S_fr / (float)(K_D * K_FR);
    }

    float th[25];
    #pragma unroll
    for (int j = 0; j < 25; ++j) th[j] = theta[part * 25 + j];

    const float dt = tvec[1] - tvec[0];

    float acc[25];
    #pragma unroll
    for (int j = 0; j < 25; ++j) acc[j] = 0.f;
    float llacc = 0.f;

    // ---- phase 1: stream X with async double-buffered LDS staging ----
    int cur = 0;
    for (int t = bid; t < NBATCH; t += GRID) {
        // barrier: vmcnt(0) drain -> buf[cur] complete; all waves done with buf[cur^1]
        __syncthreads();

        const int tn = t + GRID;
        if (tn < NBATCH)   // issue next tile's loads; they fly during compute
            stage_tile(X + (size_t)tn * TILE_F, buf[cur ^ 1], wave, lane);

        const int row = t * RPB + slot;
        const float* xp = buf[cur] + 25 * tid;   // slot*100 + part*25
        float x[25];
        float u = 0.f;
        #pragma unroll
        for (int j = 0; j < 25; ++j) { x[j] = xp[j]; u = fmaf(x[j], th[j], u); }
        u += __shfl_xor(u, 1);
        u += __shfl_xor(u, 2);   // all 4 quad lanes now hold full dot

        const float r  = __expf(u);
        const int   m  = mask[row];
        const int   rk = row - (row / K_FR) * K_FR;   // row % K_FR
        const float p  = phi_fr[rk];
        const float ck = p * ((S_fr - p) * inv_nfr - C2);
        float w, llt;
        if (m) {
            const float eneg = __expf(-dt * r);
            const float epos = __expf(dt * r);
            llt = __logf(1.0f - eneg + EPSF);
            w   = dt * r / (epos - 1.0f - EPSF);
        } else {
            llt = -dt * r;
            w   = -dt * r;
        }
        const float cw = ck * w;
        if (part == 0) llacc = fmaf(ck, llt, llacc);
        #pragma unroll
        for (int j = 0; j < 25; ++j) acc[j] = fmaf(cw, x[j], acc[j]);

        cur ^= 1;
    }
    __syncthreads();   // all compute done; safe to reuse buf[0] as scratch

    // ---- block reduce grad_theta: reuse buf[0] as red[256][25] ----
    float* red = &buf[0][0];
    #pragma unroll
    for (int j = 0; j < 25; ++j) red[tid * 25 + j] = acc[j];
    __syncthreads();
    if (tid < A_DIM) {
        const int pq = tid / 25, j = tid - pq * 25;   // a = pq*25 + j
        float s = 0.f;
        for (int sl = 0; sl < RPB; ++sl)
            s += red[(sl * 4 + pq) * 25 + j];
        ws_g[tid * GRID + bid] = s;    // plain store; kernel boundary = release
    }

    // ---- block reduce ll partial ----
    float l = llacc;
    #pragma unroll
    for (int off = 1; off < 64; off <<= 1) l += __shfl_xor(l, off);
    if (lane == 0) lsum[wave] = l;
    __syncthreads();
    if (tid == 0)
        ws_ll[bid] = lsum[0] + lsum[1] + lsum[2] + lsum[3];
}

__global__ __launch_bounds__(256)
void mmdglm_finalize(const float* __restrict__ ws_g,
                     const float* __restrict__ ws_ll,
                     float* __restrict__ out)
{
    __shared__ float fr[4];
    __shared__ double dr[4];
    const int tid = threadIdx.x, wave = tid >> 6, lane = tid & 63;
    const int b = blockIdx.x;
    if (b < A_DIM) {
        // block b reduces grad_theta component a=b over GRID partials (coalesced)
        const float* p = ws_g + (size_t)b * GRID;
        float s = p[tid] + p[tid + 256] + p[tid + 512];
        #pragma unroll
        for (int off = 1; off < 64; off <<= 1) s += __shfl_xor(s, off);
        if (lane == 0) fr[wave] = s;
        __syncthreads();
        if (tid == 0) out[1 + b] = fr[0] + fr[1] + fr[2] + fr[3];
    } else {
        // block 100: ll partials -> double -> out[0]
        double d = (double)ws_ll[tid] + (double)ws_ll[tid + 256] + (double)ws_ll[tid + 512];
        #pragma unroll
        for (int off = 1; off < 64; off <<= 1) d += __shfl_xor(d, off);
        if (lane == 0) dr[wave] = d;
        __syncthreads();
        if (tid == 0) out[0] = (float)(dr[0] + dr[1] + dr[2] + dr[3]);
    }
}

extern "C" void kernel_launch(void* const* d_in, const int* in_sizes, int n_in,
                              void* d_out, int out_size, void* d_ws, size_t ws_size,
                              hipStream_t stream) {
    const float* t      = (const float*)d_in[0];
    const int*   mask   = (const int*)  d_in[1];
    const float* X      = (const float*)d_in[2];
    const float* theta  = (const float*)d_in[3];
    const float* phi_d  = (const float*)d_in[4];
    const float* phi_fr = (const float*)d_in[5];
    float* out = (float*)d_out;

    float* ws_g  = (float*)d_ws;
    float* ws_ll = (float*)((char*)d_ws + (size_t)A_DIM * GRID * sizeof(float));

    mmdglm_main<<<GRID, 256, 0, stream>>>(X, mask, theta, t, phi_d, phi_fr,
                                          ws_g, ws_ll, out);
    mmdglm_finalize<<<A_DIM + 1, 256, 0, stream>>>(ws_g, ws_ll, out);
}